// Round 3
// baseline (20.582 us; speedup 1.0000x reference)
//
#include <hip/hip_runtime.h>

#define S 256
#define HH 512
#define WW 512

typedef float f4 __attribute__((ext_vector_type(4)));

__global__ __launch_bounds__(256) void cropface_kernel(
    const float* __restrict__ imgs,
    const float* __restrict__ bboxes,
    const int* __restrict__ has_face,
    float* __restrict__ out,
    int N)
{
#pragma clang fp contract(off)
    int t = blockIdx.x * blockDim.x + threadIdx.x;
    int total = N * (S * S / 4);            // 4 pixels per thread
    if (t >= total) return;
    int n = t >> 14;                        // / 16384
    int rem = t & 16383;
    int y = rem >> 6;                       // 64 threads per row
    int xg = (rem & 63) << 2;               // first of 4 consecutive x

    float* o0 = out + (size_t)(n * 3) * S * S + y * S + xg;

    if (has_face[n] != 1) {
        f4 z = (f4)(0.0f);
        __builtin_nontemporal_store(z, (f4*)(o0));
        __builtin_nontemporal_store(z, (f4*)(o0 + S * S));
        __builtin_nontemporal_store(z, (f4*)(o0 + 2 * S * S));
        return;
    }

    // ---- compute_bboxes (match numpy op order exactly, no FMA) ----
    float bx0 = bboxes[4 * n + 0], by0 = bboxes[4 * n + 1];
    float bx1 = bboxes[4 * n + 2], by1 = bboxes[4 * n + 3];
    float xmn = fminf(bx0, bx1), xmx = fmaxf(bx0, bx1);
    float ymn = fminf(by0, by1), ymx = fmaxf(by0, by1);
    float cx = (xmn + xmx) * 0.5f;
    float cy = (ymn + ymx) * 0.5f;
    float sxmn = (xmn - cx) * 1.5f; sxmn = sxmn + cx;
    float sxmx = (xmx - cx) * 1.5f; sxmx = sxmx + cx;
    float symn = (ymn - cy) * 1.5f; symn = symn + cy;
    float symx = (ymx - cy) * 1.5f; symx = symx + cy;
    float b0 = fmaxf(sxmn, 0.0f);   // x1
    float b1 = fmaxf(symn, 0.0f);   // y1
    float b2 = fminf(sxmx, 1.0f);   // x2
    float b3 = fminf(symx, 1.0f);   // y2

    int xmin = (int)(b0 * 512.0f);  // trunc == floor (vals >= 0)
    int ymin = (int)(b1 * 512.0f);
    int xmax = (int)(b2 * 512.0f);
    int ymax = (int)(b3 * 512.0f);
    int wci = max(xmax - xmin, 1);
    int hci = max(ymax - ymin, 1);
    float wc = (float)wci, hc = (float)hci;

    // ---- row (y) source coords, shared by the 4 pixels ----
    float ys = (float)ymin + ((float)y + 0.5f) * hc / 256.0f - 0.5f;
    ys = fminf(fmaxf(ys, (float)ymin), (float)ymin + hc - 1.0f);
    int y0 = (int)ys;
    int y1i = min(y0 + 1, ymin + hci - 1);
    float wy = ys - (float)y0;
    float omwy = 1.0f - wy;

    // ---- per-pixel column coords ----
    int x0i[4], x1i[4];
    float wxv[4];
    int xlim = xmin + wci - 1;
#pragma unroll
    for (int j = 0; j < 4; ++j) {
        float xs = (float)xmin + ((float)(xg + j) + 0.5f) * wc / 256.0f - 0.5f;
        xs = fminf(fmaxf(xs, (float)xmin), (float)xmin + wc - 1.0f);
        int x0 = (int)xs;
        x0i[j] = x0;
        x1i[j] = min(x0 + 1, xlim);
        wxv[j] = xs - (float)x0;
    }

    const float* base = imgs + (size_t)n * 3 * HH * WW;
#pragma unroll
    for (int ch = 0; ch < 3; ++ch) {
        const float* r0 = base + (size_t)ch * HH * WW + (size_t)y0 * WW;
        const float* r1 = base + (size_t)ch * HH * WW + (size_t)y1i * WW;
        // issue all 16 gathers first for memory-level parallelism
        float g00[4], g01[4], g10[4], g11[4];
#pragma unroll
        for (int j = 0; j < 4; ++j) {
            g00[j] = r0[x0i[j]];
            g01[j] = r0[x1i[j]];
            g10[j] = r1[x0i[j]];
            g11[j] = r1[x1i[j]];
        }
        f4 v;
#pragma unroll
        for (int j = 0; j < 4; ++j) {
            float wx = wxv[j];
            float omwx = 1.0f - wx;
            float acc = (omwy * omwx) * g00[j];
            acc = acc + (omwy * wx) * g01[j];
            acc = acc + (wy * omwx) * g10[j];
            acc = acc + (wy * wx) * g11[j];
            v[j] = acc;
        }
        __builtin_nontemporal_store(v, (f4*)(o0 + ch * S * S));
    }
}

extern "C" void kernel_launch(void* const* d_in, const int* in_sizes, int n_in,
                              void* d_out, int out_size, void* d_ws, size_t ws_size,
                              hipStream_t stream) {
    const float* imgs     = (const float*)d_in[0];
    const float* bboxes   = (const float*)d_in[1];
    const int*   has_face = (const int*)d_in[2];
    float* out = (float*)d_out;
    int N = in_sizes[2];                      // 32 images
    int total = N * (S * S / 4);              // 4 px per thread
    int block = 256;
    int grid = (total + block - 1) / block;
    cropface_kernel<<<grid, block, 0, stream>>>(imgs, bboxes, has_face, out, N);
}

// Round 4
// 14.276 us; speedup vs baseline: 1.4418x; 1.4418x over previous
//
#include <hip/hip_runtime.h>

#define S 256
#define HH 512
#define WW 512

__global__ __launch_bounds__(256) void cropface_kernel(
    const float* __restrict__ imgs,
    const float* __restrict__ bboxes,
    const int* __restrict__ has_face,
    float* __restrict__ out)
{
#pragma clang fp contract(off)
    // --- bijective chunked XCD swizzle: XCD(bid)=bid%8 gets a contiguous
    // --- range of work ids -> adjacent output rows share the same L2.
    int nwg = gridDim.x;
    int q = nwg >> 3, r = nwg & 7;
    int xcd = blockIdx.x & 7, idx = blockIdx.x >> 3;
    int w = (xcd < r ? xcd * (q + 1) : r * (q + 1) + (xcd - r) * q) + idx;

    int n = w >> 8;            // image (256 row-blocks per image)
    int y = w & 255;           // output row
    int x = threadIdx.x;       // output col (1 px/thread, round-1 coalescing)

    float* o0 = out + (size_t)(n * 3) * S * S + y * S + x;

    if (has_face[n] != 1) {
        __builtin_nontemporal_store(0.0f, o0);
        __builtin_nontemporal_store(0.0f, o0 + S * S);
        __builtin_nontemporal_store(0.0f, o0 + 2 * S * S);
        return;
    }

    // ---- compute_bboxes (match numpy op order exactly, no FMA) ----
    float bx0 = bboxes[4 * n + 0], by0 = bboxes[4 * n + 1];
    float bx1 = bboxes[4 * n + 2], by1 = bboxes[4 * n + 3];
    float xmn = fminf(bx0, bx1), xmx = fmaxf(bx0, bx1);
    float ymn = fminf(by0, by1), ymx = fmaxf(by0, by1);
    float cx = (xmn + xmx) * 0.5f;
    float cy = (ymn + ymx) * 0.5f;
    float sxmn = (xmn - cx) * 1.5f; sxmn = sxmn + cx;
    float sxmx = (xmx - cx) * 1.5f; sxmx = sxmx + cx;
    float symn = (ymn - cy) * 1.5f; symn = symn + cy;
    float symx = (ymx - cy) * 1.5f; symx = symx + cy;
    float b0 = fmaxf(sxmn, 0.0f);   // x1
    float b1 = fmaxf(symn, 0.0f);   // y1
    float b2 = fminf(sxmx, 1.0f);   // x2
    float b3 = fminf(symx, 1.0f);   // y2

    int xmin = (int)(b0 * 512.0f);  // trunc == floor (vals >= 0)
    int ymin = (int)(b1 * 512.0f);
    int xmax = (int)(b2 * 512.0f);
    int ymax = (int)(b3 * 512.0f);
    int wci = max(xmax - xmin, 1);
    int hci = max(ymax - ymin, 1);
    float wc = (float)wci, hc = (float)hci;

    // ---- bilinear source coords (exact in fp32) ----
    float ys = (float)ymin + ((float)y + 0.5f) * hc / 256.0f - 0.5f;
    ys = fminf(fmaxf(ys, (float)ymin), (float)ymin + hc - 1.0f);
    float xs = (float)xmin + ((float)x + 0.5f) * wc / 256.0f - 0.5f;
    xs = fminf(fmaxf(xs, (float)xmin), (float)xmin + wc - 1.0f);

    int y0 = (int)ys;               // trunc == floor (vals >= 0)
    int x0 = (int)xs;
    int y1i = min(y0 + 1, ymin + hci - 1);
    int x1i = min(x0 + 1, xmin + wci - 1);
    float wy = ys - (float)y0;
    float wx = xs - (float)x0;
    float w00 = (1.0f - wy) * (1.0f - wx);
    float w01 = (1.0f - wy) * wx;
    float w10 = wy * (1.0f - wx);
    float w11 = wy * wx;

    const float* base = imgs + (size_t)n * 3 * HH * WW;
#pragma unroll
    for (int ch = 0; ch < 3; ++ch) {
        const float* p = base + (size_t)ch * HH * WW;
        float g00 = p[y0  * WW + x0 ];
        float g01 = p[y0  * WW + x1i];
        float g10 = p[y1i * WW + x0 ];
        float g11 = p[y1i * WW + x1i];
        float acc = w00 * g00;
        acc = acc + w01 * g01;
        acc = acc + w10 * g10;
        acc = acc + w11 * g11;
        __builtin_nontemporal_store(acc, o0 + ch * S * S);
    }
}

extern "C" void kernel_launch(void* const* d_in, const int* in_sizes, int n_in,
                              void* d_out, int out_size, void* d_ws, size_t ws_size,
                              hipStream_t stream) {
    const float* imgs     = (const float*)d_in[0];
    const float* bboxes   = (const float*)d_in[1];
    const int*   has_face = (const int*)d_in[2];
    float* out = (float*)d_out;
    int N = in_sizes[2];                 // 32 images
    int grid = N * 256;                  // one block per output row
    cropface_kernel<<<grid, 256, 0, stream>>>(imgs, bboxes, has_face, out);
}

// Round 5
// 14.032 us; speedup vs baseline: 1.4668x; 1.0174x over previous
//
#include <hip/hip_runtime.h>

#define S 256
#define HH 512
#define WW 512

__global__ __launch_bounds__(256) void cropface_kernel(
    const float* __restrict__ imgs,
    const float* __restrict__ bboxes,
    const int* __restrict__ has_face,
    float* __restrict__ out)
{
#pragma clang fp contract(off)
    // bijective chunked XCD swizzle (nwg divisible by 8 here)
    int nwg = gridDim.x;
    int q = nwg >> 3, r = nwg & 7;
    int xcd = blockIdx.x & 7, idx = blockIdx.x >> 3;
    int w = (xcd < r ? xcd * (q + 1) : r * (q + 1) + (xcd - r) * q) + idx;

    int n = w >> 7;                 // image (128 row-pairs per image)
    int ybase = (w & 127) << 1;     // first of 2 output rows
    int x = threadIdx.x;            // output col, 1 px/thread (coalesced)

    float* o0 = out + (size_t)(n * 3) * S * S + ybase * S + x;

    if (has_face[n] != 1) {
#pragma unroll
        for (int ch = 0; ch < 3; ++ch) {
            __builtin_nontemporal_store(0.0f, o0 + ch * S * S);
            __builtin_nontemporal_store(0.0f, o0 + ch * S * S + S);
        }
        return;
    }

    // ---- compute_bboxes (numpy op order, no FMA) — uniform per block ----
    float bx0 = bboxes[4 * n + 0], by0 = bboxes[4 * n + 1];
    float bx1 = bboxes[4 * n + 2], by1 = bboxes[4 * n + 3];
    float xmn = fminf(bx0, bx1), xmx = fmaxf(bx0, bx1);
    float ymn = fminf(by0, by1), ymx = fmaxf(by0, by1);
    float cx = (xmn + xmx) * 0.5f;
    float cy = (ymn + ymx) * 0.5f;
    float sxmn = (xmn - cx) * 1.5f; sxmn = sxmn + cx;
    float sxmx = (xmx - cx) * 1.5f; sxmx = sxmx + cx;
    float symn = (ymn - cy) * 1.5f; symn = symn + cy;
    float symx = (ymx - cy) * 1.5f; symx = symx + cy;
    float b0 = fmaxf(sxmn, 0.0f);
    float b1 = fmaxf(symn, 0.0f);
    float b2 = fminf(sxmx, 1.0f);
    float b3 = fminf(symx, 1.0f);

    int xmin = (int)(b0 * 512.0f);
    int ymin = (int)(b1 * 512.0f);
    int xmax = (int)(b2 * 512.0f);
    int ymax = (int)(b3 * 512.0f);
    int wci = max(xmax - xmin, 1);
    int hci = max(ymax - ymin, 1);
    float wc = (float)wci, hc = (float)hci;

    // ---- column coords: y-independent, computed ONCE for both rows ----
    float xs = (float)xmin + ((float)x + 0.5f) * wc / 256.0f - 0.5f;
    xs = fminf(fmaxf(xs, (float)xmin), (float)xmin + wc - 1.0f);
    int x0 = (int)xs;
    int x1i = min(x0 + 1, xmin + wci - 1);
    float wx = xs - (float)x0;
    float omwx = 1.0f - wx;

    // ---- row coords for the 2 rows ----
    int y0v[2], y1v[2];
    float wyv[2];
    int ylim = ymin + hci - 1;
#pragma unroll
    for (int rr = 0; rr < 2; ++rr) {
        float ys = (float)ymin + ((float)(ybase + rr) + 0.5f) * hc / 256.0f - 0.5f;
        ys = fminf(fmaxf(ys, (float)ymin), (float)ymin + hc - 1.0f);
        int y0 = (int)ys;
        y0v[rr] = y0;
        y1v[rr] = min(y0 + 1, ylim);
        wyv[rr] = ys - (float)y0;
    }

    const float* base = imgs + (size_t)n * 3 * HH * WW;
#pragma unroll
    for (int ch = 0; ch < 3; ++ch) {
        const float* p = base + (size_t)ch * HH * WW;
        // burst of 8 independent gathers (2 rows x 4 taps) for MLP
        float g00[2], g01[2], g10[2], g11[2];
#pragma unroll
        for (int rr = 0; rr < 2; ++rr) {
            const float* r0 = p + (size_t)y0v[rr] * WW;
            const float* r1 = p + (size_t)y1v[rr] * WW;
            g00[rr] = r0[x0];
            g01[rr] = r0[x1i];
            g10[rr] = r1[x0];
            g11[rr] = r1[x1i];
        }
#pragma unroll
        for (int rr = 0; rr < 2; ++rr) {
            float wy = wyv[rr];
            float omwy = 1.0f - wy;
            float acc = (omwy * omwx) * g00[rr];
            acc = acc + (omwy * wx) * g01[rr];
            acc = acc + (wy * omwx) * g10[rr];
            acc = acc + (wy * wx) * g11[rr];
            __builtin_nontemporal_store(acc, o0 + ch * S * S + rr * S);
        }
    }
}

extern "C" void kernel_launch(void* const* d_in, const int* in_sizes, int n_in,
                              void* d_out, int out_size, void* d_ws, size_t ws_size,
                              hipStream_t stream) {
    const float* imgs     = (const float*)d_in[0];
    const float* bboxes   = (const float*)d_in[1];
    const int*   has_face = (const int*)d_in[2];
    float* out = (float*)d_out;
    int N = in_sizes[2];                 // 32 images
    int grid = N * 128;                  // one block per 2 output rows
    cropface_kernel<<<grid, 256, 0, stream>>>(imgs, bboxes, has_face, out);
}

// Round 6
// 12.597 us; speedup vs baseline: 1.6339x; 1.1140x over previous
//
#include <hip/hip_runtime.h>

#define S 256
#define HH 512
#define WW 512

typedef float f2 __attribute__((ext_vector_type(2), aligned(4)));

__global__ __launch_bounds__(256) void cropface_kernel(
    const float* __restrict__ imgs,
    const float* __restrict__ bboxes,
    const int* __restrict__ has_face,
    float* __restrict__ out)
{
#pragma clang fp contract(off)
    // bijective chunked XCD swizzle (nwg divisible by 8 here)
    int nwg = gridDim.x;
    int q = nwg >> 3, r = nwg & 7;
    int xcd = blockIdx.x & 7, idx = blockIdx.x >> 3;
    int w = (xcd < r ? xcd * (q + 1) : r * (q + 1) + (xcd - r) * q) + idx;

    int n = w >> 7;                 // image (128 row-pairs per image)
    int ybase = (w & 127) << 1;     // first of 2 output rows
    int x = threadIdx.x;            // output col, 1 px/thread (coalesced)

    float* o0 = out + (size_t)(n * 3) * S * S + ybase * S + x;

    if (has_face[n] != 1) {
#pragma unroll
        for (int ch = 0; ch < 3; ++ch) {
            __builtin_nontemporal_store(0.0f, o0 + ch * S * S);
            __builtin_nontemporal_store(0.0f, o0 + ch * S * S + S);
        }
        return;
    }

    // ---- compute_bboxes (numpy op order, no FMA) ----
    float bx0 = bboxes[4 * n + 0], by0 = bboxes[4 * n + 1];
    float bx1 = bboxes[4 * n + 2], by1 = bboxes[4 * n + 3];
    float xmn = fminf(bx0, bx1), xmx = fmaxf(bx0, bx1);
    float ymn = fminf(by0, by1), ymx = fmaxf(by0, by1);
    float cx = (xmn + xmx) * 0.5f;
    float cy = (ymn + ymx) * 0.5f;
    float sxmn = (xmn - cx) * 1.5f; sxmn = sxmn + cx;
    float sxmx = (xmx - cx) * 1.5f; sxmx = sxmx + cx;
    float symn = (ymn - cy) * 1.5f; symn = symn + cy;
    float symx = (ymx - cy) * 1.5f; symx = symx + cy;
    float b0 = fmaxf(sxmn, 0.0f);
    float b1 = fmaxf(symn, 0.0f);
    float b2 = fminf(sxmx, 1.0f);
    float b3 = fminf(symx, 1.0f);

    int xmin = (int)(b0 * 512.0f);
    int ymin = (int)(b1 * 512.0f);
    int xmax = (int)(b2 * 512.0f);
    int ymax = (int)(b3 * 512.0f);
    int wci = max(xmax - xmin, 1);
    int hci = max(ymax - ymin, 1);
    float wc = (float)wci, hc = (float)hci;

    // ---- column coords (y-independent, once for both rows) ----
    float xs = (float)xmin + ((float)x + 0.5f) * wc / 256.0f - 0.5f;
    xs = fminf(fmaxf(xs, (float)xmin), (float)xmin + wc - 1.0f);
    int x0 = (int)xs;
    float wx = xs - (float)x0;       // wx==0 whenever x0 would need clamping
    float omwx = 1.0f - wx;
    int pbase = min(x0, 510);        // paired-tap load base, always in-row
    bool hi = (x0 > 510);            // x0==511 -> the wanted tap is pair.y

    // ---- row coords for the 2 rows ----
    int y0v[2], y1v[2];
    float wyv[2];
#pragma unroll
    for (int rr = 0; rr < 2; ++rr) {
        float ys = (float)ymin + ((float)(ybase + rr) + 0.5f) * hc / 256.0f - 0.5f;
        ys = fminf(fmaxf(ys, (float)ymin), (float)ymin + hc - 1.0f);
        int y0 = (int)ys;
        y0v[rr] = y0;
        y1v[rr] = min(y0 + 1, 511);  // wy==0 whenever clamp would engage
        wyv[rr] = ys - (float)y0;
    }

    const float* base = imgs + (size_t)n * 3 * HH * WW;
#pragma unroll
    for (int ch = 0; ch < 3; ++ch) {
        const float* p = base + (size_t)ch * HH * WW;
        // 4 paired loads (2 rows x 2 src-rows), issued together for MLP
        f2 a0[2], a1[2];
#pragma unroll
        for (int rr = 0; rr < 2; ++rr) {
            a0[rr] = *(const f2*)(p + (size_t)y0v[rr] * WW + pbase);
            a1[rr] = *(const f2*)(p + (size_t)y1v[rr] * WW + pbase);
        }
#pragma unroll
        for (int rr = 0; rr < 2; ++rr) {
            float g00 = hi ? a0[rr].y : a0[rr].x;
            float g01 = a0[rr].y;
            float g10 = hi ? a1[rr].y : a1[rr].x;
            float g11 = a1[rr].y;
            float wy = wyv[rr];
            float omwy = 1.0f - wy;
            float acc = (omwy * omwx) * g00;
            acc = acc + (omwy * wx) * g01;
            acc = acc + (wy * omwx) * g10;
            acc = acc + (wy * wx) * g11;
            __builtin_nontemporal_store(acc, o0 + ch * S * S + rr * S);
        }
    }
}

extern "C" void kernel_launch(void* const* d_in, const int* in_sizes, int n_in,
                              void* d_out, int out_size, void* d_ws, size_t ws_size,
                              hipStream_t stream) {
    const float* imgs     = (const float*)d_in[0];
    const float* bboxes   = (const float*)d_in[1];
    const int*   has_face = (const int*)d_in[2];
    float* out = (float*)d_out;
    int N = in_sizes[2];                 // 32 images
    int grid = N * 128;                  // one block per 2 output rows
    cropface_kernel<<<grid, 256, 0, stream>>>(imgs, bboxes, has_face, out);
}

// Round 7
// 11.144 us; speedup vs baseline: 1.8469x; 1.1303x over previous
//
#include <hip/hip_runtime.h>

#define S 256
#define HH 512
#define WW 512

typedef float f4 __attribute__((ext_vector_type(4), aligned(4)));
typedef float f2 __attribute__((ext_vector_type(2), aligned(8)));

__global__ __launch_bounds__(256) void cropface_kernel(
    const float* __restrict__ imgs,
    const float* __restrict__ bboxes,
    const int* __restrict__ has_face,
    float* __restrict__ out)
{
    // bijective chunked XCD swizzle (nwg = 2048, divisible by 8)
    int nwg = gridDim.x;
    int q = nwg >> 3, r = nwg & 7;
    int xcd = blockIdx.x & 7, idx = blockIdx.x >> 3;
    int w = (xcd < r ? xcd * (q + 1) : r * (q + 1) + (xcd - r) * q) + idx;

    int n = w >> 6;                  // image (64 blocks per image)
    int rowg = (w & 63) << 2;        // block's first output row (4 rows/block)
    int t = threadIdx.x;
    int tx = t & 127;                // x-pair index (covers 256 px)
    int ty = t >> 7;                 // which row-pair within the block
    int ybase = rowg + (ty << 1);    // thread's first output row
    int xg = tx << 1;                // thread's first output col

    float* o0 = out + (size_t)(n * 3) * S * S + ybase * S + xg;

    if (has_face[n] != 1) {
        f2 z; z.x = 0.0f; z.y = 0.0f;
#pragma unroll
        for (int ch = 0; ch < 3; ++ch) {
            __builtin_nontemporal_store(z, (f2*)(o0 + ch * S * S));
            __builtin_nontemporal_store(z, (f2*)(o0 + ch * S * S + S));
        }
        return;
    }

    // ---- bbox integers: must match numpy bit-exactly (discontinuous) ----
    int xmin, ymin, wci, hci;
    float wc, hc;
    {
#pragma clang fp contract(off)
        float bx0 = bboxes[4 * n + 0], by0 = bboxes[4 * n + 1];
        float bx1 = bboxes[4 * n + 2], by1 = bboxes[4 * n + 3];
        float xmn = fminf(bx0, bx1), xmx = fmaxf(bx0, bx1);
        float ymn = fminf(by0, by1), ymx = fmaxf(by0, by1);
        float cx = (xmn + xmx) * 0.5f;
        float cy = (ymn + ymx) * 0.5f;
        float sxmn = (xmn - cx) * 1.5f; sxmn = sxmn + cx;
        float sxmx = (xmx - cx) * 1.5f; sxmx = sxmx + cx;
        float symn = (ymn - cy) * 1.5f; symn = symn + cy;
        float symx = (ymx - cy) * 1.5f; symx = symx + cy;
        float b0 = fmaxf(sxmn, 0.0f);
        float b1 = fmaxf(symn, 0.0f);
        float b2 = fminf(sxmx, 1.0f);
        float b3 = fminf(symx, 1.0f);
        xmin = (int)(b0 * 512.0f);
        ymin = (int)(b1 * 512.0f);
        int xmax = (int)(b2 * 512.0f);
        int ymax = (int)(b3 * 512.0f);
        wci = max(xmax - xmin, 1);
        hci = max(ymax - ymin, 1);
        wc = (float)wci;
        hc = (float)hci;
    }

    // ---- x coords for the pair (continuous path: fast math OK) ----
    float xlo = (float)xmin, xhi = (float)xmin + wc - 1.0f;
    float xs0 = (float)xmin + ((float)xg + 0.5f) * wc / 256.0f - 0.5f;
    xs0 = fminf(fmaxf(xs0, xlo), xhi);
    float xs1 = (float)xmin + ((float)(xg + 1) + 0.5f) * wc / 256.0f - 0.5f;
    xs1 = fminf(fmaxf(xs1, xlo), xhi);
    int pbase = min((int)xs0, 508);            // dwordx4 window [pbase, pbase+3]
    float pb = (float)pbase;
    float xi0 = xs0 - pb;                      // in [0,3]
    float xi1 = xs1 - pb;                      // in [0,3]
    // hat weights: exactly omwx/wx at the two active slots, 0 elsewhere
    f4 wv0, wv1;
#pragma unroll
    for (int k = 0; k < 4; ++k) {
        wv0[k] = fmaxf(0.0f, 1.0f - fabsf(xi0 - (float)k));
        wv1[k] = fmaxf(0.0f, 1.0f - fabsf(xi1 - (float)k));
    }

    // ---- y coords for the 2 output rows ----
    float ylo = (float)ymin, yhic = (float)ymin + hc - 1.0f;
    int y0v[2], y1v[2];
    float wyv[2];
#pragma unroll
    for (int rr = 0; rr < 2; ++rr) {
        float ys = (float)ymin + ((float)(ybase + rr) + 0.5f) * hc / 256.0f - 0.5f;
        ys = fminf(fmaxf(ys, ylo), yhic);
        int y0 = (int)ys;
        y0v[rr] = y0;
        y1v[rr] = min(y0 + 1, 511);            // weight is 0 whenever clamped
        wyv[rr] = ys - (float)y0;
    }

    const float* base = imgs + (size_t)n * 3 * HH * WW;
#pragma unroll
    for (int ch = 0; ch < 3; ++ch) {
        const float* p = base + (size_t)ch * HH * WW;
        f4 va[2], vb[2];
#pragma unroll
        for (int rr = 0; rr < 2; ++rr) {       // issue all 4 loads for MLP
            va[rr] = *(const f4*)(p + (size_t)y0v[rr] * WW + pbase);
            vb[rr] = *(const f4*)(p + (size_t)y1v[rr] * WW + pbase);
        }
#pragma unroll
        for (int rr = 0; rr < 2; ++rr) {
            float d00 = ((va[rr].x * wv0.x + va[rr].y * wv0.y) + va[rr].z * wv0.z) + va[rr].w * wv0.w;
            float d01 = ((va[rr].x * wv1.x + va[rr].y * wv1.y) + va[rr].z * wv1.z) + va[rr].w * wv1.w;
            float d10 = ((vb[rr].x * wv0.x + vb[rr].y * wv0.y) + vb[rr].z * wv0.z) + vb[rr].w * wv0.w;
            float d11 = ((vb[rr].x * wv1.x + vb[rr].y * wv1.y) + vb[rr].z * wv1.z) + vb[rr].w * wv1.w;
            float wy = wyv[rr], omwy = 1.0f - wy;
            f2 st;
            st.x = omwy * d00 + wy * d10;
            st.y = omwy * d01 + wy * d11;
            __builtin_nontemporal_store(st, (f2*)(o0 + ch * S * S + rr * S));
        }
    }
}

extern "C" void kernel_launch(void* const* d_in, const int* in_sizes, int n_in,
                              void* d_out, int out_size, void* d_ws, size_t ws_size,
                              hipStream_t stream) {
    const float* imgs     = (const float*)d_in[0];
    const float* bboxes   = (const float*)d_in[1];
    const int*   has_face = (const int*)d_in[2];
    float* out = (float*)d_out;
    int N = in_sizes[2];                 // 32 images
    int grid = N * 64;                   // 4 output rows per block
    cropface_kernel<<<grid, 256, 0, stream>>>(imgs, bboxes, has_face, out);
}

// Round 8
// 10.958 us; speedup vs baseline: 1.8783x; 1.0170x over previous
//
#include <hip/hip_runtime.h>

#define S 256
#define HH 512
#define WW 512

typedef float f4 __attribute__((ext_vector_type(4), aligned(4)));
typedef float f4a __attribute__((ext_vector_type(4), aligned(16)));

__global__ __launch_bounds__(256) void cropface_kernel(
    const float* __restrict__ imgs,
    const float* __restrict__ bboxes,
    const int* __restrict__ has_face,
    float* __restrict__ out)
{
    // bijective chunked XCD swizzle (nwg = 1024, divisible by 8)
    int nwg = gridDim.x;
    int q = nwg >> 3, r = nwg & 7;
    int xcd = blockIdx.x & 7, idx = blockIdx.x >> 3;
    int w = (xcd < r ? xcd * (q + 1) : r * (q + 1) + (xcd - r) * q) + idx;

    int n = w >> 5;                  // image (32 blocks per image)
    int rowg = (w & 31) << 3;        // block's first output row (8 rows/block)
    int t = threadIdx.x;
    int tx = t & 63;                 // x-quad index (64 quads cover 256 px)
    int ty = t >> 6;                 // row-pair within the block (4 pairs)
    int ybase = rowg + (ty << 1);    // thread's first output row
    int xg = tx << 2;                // thread's first output col (4 px)

    float* o0 = out + (size_t)(n * 3) * S * S + ybase * S + xg;

    if (has_face[n] != 1) {
        f4a z = (f4a)(0.0f);
#pragma unroll
        for (int ch = 0; ch < 3; ++ch) {
            __builtin_nontemporal_store(z, (f4a*)(o0 + ch * S * S));
            __builtin_nontemporal_store(z, (f4a*)(o0 + ch * S * S + S));
        }
        return;
    }

    // ---- bbox integers: must match numpy bit-exactly (discontinuous) ----
    int xmin, ymin, wci, hci;
    float wc, hc;
    {
#pragma clang fp contract(off)
        float bx0 = bboxes[4 * n + 0], by0 = bboxes[4 * n + 1];
        float bx1 = bboxes[4 * n + 2], by1 = bboxes[4 * n + 3];
        float xmn = fminf(bx0, bx1), xmx = fmaxf(bx0, bx1);
        float ymn = fminf(by0, by1), ymx = fmaxf(by0, by1);
        float cx = (xmn + xmx) * 0.5f;
        float cy = (ymn + ymx) * 0.5f;
        float sxmn = (xmn - cx) * 1.5f; sxmn = sxmn + cx;
        float sxmx = (xmx - cx) * 1.5f; sxmx = sxmx + cx;
        float symn = (ymn - cy) * 1.5f; symn = symn + cy;
        float symx = (ymx - cy) * 1.5f; symx = symx + cy;
        float b0 = fmaxf(sxmn, 0.0f);
        float b1 = fmaxf(symn, 0.0f);
        float b2 = fminf(sxmx, 1.0f);
        float b3 = fminf(symx, 1.0f);
        xmin = (int)(b0 * 512.0f);
        ymin = (int)(b1 * 512.0f);
        int xmax = (int)(b2 * 512.0f);
        int ymax = (int)(b3 * 512.0f);
        wci = max(xmax - xmin, 1);
        hci = max(ymax - ymin, 1);
        wc = (float)wci;
        hc = (float)hci;
    }

    // ---- x coords for 4 px; two independent 4-float windows (pairs) ----
    float xlo = (float)xmin, xhi = (float)xmin + wc - 1.0f;
    float xsv[4];
#pragma unroll
    for (int j = 0; j < 4; ++j) {
        float xs = (float)xmin + ((float)(xg + j) + 0.5f) * wc / 256.0f - 0.5f;
        xsv[j] = fminf(fmaxf(xs, xlo), xhi);
    }
    int pbA = min((int)xsv[0], 508);     // window for px {0,1}
    int pbB = min((int)xsv[2], 508);     // window for px {2,3}
    f4 wv[4];                            // hat weights per px in its window
#pragma unroll
    for (int j = 0; j < 4; ++j) {
        float pb = (float)(j < 2 ? pbA : pbB);
        float xi = xsv[j] - pb;          // in [0,3]
#pragma unroll
        for (int k = 0; k < 4; ++k)
            wv[j][k] = fmaxf(0.0f, 1.0f - fabsf(xi - (float)k));
    }

    // ---- y coords for the 2 output rows ----
    float ylo = (float)ymin, yhic = (float)ymin + hc - 1.0f;
    int y0v[2], y1v[2];
    float wyv[2];
#pragma unroll
    for (int rr = 0; rr < 2; ++rr) {
        float ys = (float)ymin + ((float)(ybase + rr) + 0.5f) * hc / 256.0f - 0.5f;
        ys = fminf(fmaxf(ys, ylo), yhic);
        int y0 = (int)ys;
        y0v[rr] = y0;
        y1v[rr] = min(y0 + 1, 511);      // weight is 0 whenever clamped
        wyv[rr] = ys - (float)y0;
    }

    const float* base = imgs + (size_t)n * 3 * HH * WW;
#pragma unroll
    for (int ch = 0; ch < 3; ++ch) {
        const float* p = base + (size_t)ch * HH * WW;
        // 8 loads per channel (2 rows x 2 src-rows x 2 windows), all issued first
        f4 vA0[2], vA1[2], vB0[2], vB1[2];
#pragma unroll
        for (int rr = 0; rr < 2; ++rr) {
            const float* r0 = p + (size_t)y0v[rr] * WW;
            const float* r1 = p + (size_t)y1v[rr] * WW;
            vA0[rr] = *(const f4*)(r0 + pbA);
            vB0[rr] = *(const f4*)(r0 + pbB);
            vA1[rr] = *(const f4*)(r1 + pbA);
            vB1[rr] = *(const f4*)(r1 + pbB);
        }
#pragma unroll
        for (int rr = 0; rr < 2; ++rr) {
            float wy = wyv[rr], omwy = 1.0f - wy;
            f4a st;
#pragma unroll
            for (int j = 0; j < 4; ++j) {
                const f4& top = (j < 2) ? vA0[rr] : vB0[rr];
                const f4& bot = (j < 2) ? vA1[rr] : vB1[rr];
                float dt = ((top.x * wv[j].x + top.y * wv[j].y) + top.z * wv[j].z) + top.w * wv[j].w;
                float db = ((bot.x * wv[j].x + bot.y * wv[j].y) + bot.z * wv[j].z) + bot.w * wv[j].w;
                st[j] = omwy * dt + wy * db;
            }
            __builtin_nontemporal_store(st, (f4a*)(o0 + ch * S * S + rr * S));
        }
    }
}

extern "C" void kernel_launch(void* const* d_in, const int* in_sizes, int n_in,
                              void* d_out, int out_size, void* d_ws, size_t ws_size,
                              hipStream_t stream) {
    const float* imgs     = (const float*)d_in[0];
    const float* bboxes   = (const float*)d_in[1];
    const int*   has_face = (const int*)d_in[2];
    float* out = (float*)d_out;
    int N = in_sizes[2];                 // 32 images
    int grid = N * 32;                   // 8 output rows per block
    cropface_kernel<<<grid, 256, 0, stream>>>(imgs, bboxes, has_face, out);
}